// Round 2
// baseline (249.922 us; speedup 1.0000x reference)
//
#include <hip/hip_runtime.h>
#include <hip/hip_bf16.h>
#include <cstdint>
#include <cstddef>

typedef __hip_bfloat16 bf16;
typedef __attribute__((ext_vector_type(8))) short bf16x8;
typedef __attribute__((ext_vector_type(4))) float floatx4;

static constexpr int Bb = 2;
static constexpr int Ls = 4096;
static constexpr int Dm = 1024;
static constexpr int Hn = 16;
static constexpr int HD = 64;
static constexpr int BS = 256;
static constexpr int QKVROW = 3 * Dm;  // 3072
static constexpr int KRP = 72;         // padded roped-K row stride (16B-aligned, breaks bank stride)

static constexpr size_t NX  = (size_t)8192 * 1024;
static constexpr size_t NQ  = (size_t)8192 * 3072;
static constexpr size_t NW1 = (size_t)3072 * 1024;
static constexpr size_t NW2 = (size_t)1024 * 1024;

__device__ __forceinline__ void async_load16(const void* g, void* l) {
  __builtin_amdgcn_global_load_lds(
      (__attribute__((address_space(1))) void*)(void*)(g),
      (__attribute__((address_space(3))) void*)(l), 16, 0, 0);
}

__device__ __forceinline__ short f2bf(float f) {
  union { __hip_bfloat16 b; short s; } u;
  u.b = __float2bfloat16(f);
  return u.s;
}

__device__ __forceinline__ float bf2f(short s) {
  union { unsigned u; float f; } v;
  v.u = ((unsigned)(unsigned short)s) << 16;
  return v.f;
}

__device__ __forceinline__ bf16x8 load8(const float* p) {
  const float4 f0 = *(const float4*)(const void*)p;
  const float4 f1 = *(const float4*)(const void*)(p + 4);
  bf16x8 r;
  r[0] = f2bf(f0.x); r[1] = f2bf(f0.y); r[2] = f2bf(f0.z); r[3] = f2bf(f0.w);
  r[4] = f2bf(f1.x); r[5] = f2bf(f1.y); r[6] = f2bf(f1.z); r[7] = f2bf(f1.w);
  return r;
}

__device__ __forceinline__ void storeC(bf16* C, size_t idx, float v) {
  C[idx] = __float2bfloat16(v);
}
__device__ __forceinline__ void storeC(float* C, size_t idx, float v) {
  C[idx] = v;
}

// Merged fp32->bf16 convert for x, Wqkv, Wout (regions 2048-aligned; block-uniform branch).
__global__ void cvt3_kernel(const float* __restrict__ x, const float* __restrict__ w1,
                            const float* __restrict__ w2, bf16* __restrict__ xb,
                            bf16* __restrict__ w1b, bf16* __restrict__ w2b) {
  const size_t i = ((size_t)blockIdx.x * 256 + threadIdx.x) * 8;
  if (i < NX) {
    *(bf16x8*)(void*)((short*)(void*)xb + i) = load8(x + i);
  } else if (i < NX + NW1) {
    const size_t k = i - NX;
    *(bf16x8*)(void*)((short*)(void*)w1b + k) = load8(w1 + k);
  } else {
    const size_t k = i - NX - NW1;
    *(bf16x8*)(void*)((short*)(void*)w2b + k) = load8(w2 + k);
  }
}

// ---------------------------------------------------------------------------
// 8-phase 256x128 bf16 GEMM (T3+T4+T5+T2), C[m,n] = sum_k A[m,k]*B[n,k].
// M%256==0, N%128==0, K%64==0.
//
// Round-1 post-mortem: flat 1-barrier counted-vmcnt landed at 654 TF = the
// documented 2-phase ceiling (m233: stage+vmcnt+barrier = 72% of critical
// path). T2/T4/T5 are regime-gated on the 8-phase interleave -> this is the
// m201-lineage schedule adapted to BM=256,BN=128 (exact grids for both GEMMs).
//
// Geometry: 8 waves as 4M x 2N, per-wave C = 64x64. K-tile BK=64 split into
// 4 C-quadrant phases (Gray order): P0=(m0,n1) P1=(m0,n0) P2=(m1,n0) P3=(m1,n1).
// LDS: full double-buffer, region-structured:
//   sA[buf][mi][128][64]  (mi = (row&63)>>5 band)   64 KB
//   sB[buf][ni][ 64][64]  (ni = (row&63)>>5 band)   32 KB
// Staging: ONE region of tile t+1 per phase (P0:Bn1=1 load, P1:Am0=2,
// P2:Bn0=1, P3:Am1=2; 6 loads/thread/tile), prefetch distance 3-4 phases.
// vmcnt ledger (per wave, stage issued BEFORE wait): steady (4,5,4,-),
// peeled last tile (3,2,0,-). Never drains in main loop (T4).
// Write-after-read: each region's restage is >=1 barrier after its last read
// (region r staged in the same phase-slot where r of tile t-1 was last read,
// one full tile earlier).
// T2 swizzle: phys 16B-slot = logical-slot ^ (i&7), applied on the GLOBAL
// source at stage (i&7 == tid>>3 &7) and on the ds_read address (i&7 == l15&7)
// -> fragment read = 8 slots x 2 lanes/bank-group = 2-way = free.
// ---------------------------------------------------------------------------
template <typename TC>
__global__ __launch_bounds__(512, 2) void gemm_8p(
    const bf16* __restrict__ A, const bf16* __restrict__ Bm, TC* __restrict__ C,
    int M, int N, int K) {
  constexpr int BK = 64;
  __shared__ __align__(16) short sA[2][2][128 * 64];  // 64 KB
  __shared__ __align__(16) short sB[2][2][64 * 64];   // 32 KB
  const int tid = threadIdx.x;
  const int wave = tid >> 6, lane = tid & 63;
  const int quad = lane >> 4, l15 = lane & 15;
  const int wr = wave >> 1, wc = wave & 1;
  const int tm = blockIdx.y * 256, tn = blockIdx.x * 128;

  // ---- staging geometry (per thread) ----
  const int iLo = tid >> 3;            // region row index, load 0 (0..63)
  const int csP = tid & 7;             // physical 16B slot this thread fills
  const int csL = csP ^ (iLo & 7);     // logical (global) slot -> pre-swizzled source
  const bf16* gA[2][2];                // [mi][j]
  const bf16* gB[2];                   // [ni]
#pragma unroll
  for (int mi = 0; mi < 2; mi++) {
#pragma unroll
    for (int j = 0; j < 2; j++) {
      const int i = iLo + j * 64;
      const int r = (i >> 5) * 64 + mi * 32 + (i & 31);
      gA[mi][j] = A + (size_t)(tm + r) * K + csL * 8;
    }
    const int rB = (iLo >> 5) * 64 + mi * 32 + (iLo & 31);
    gB[mi] = Bm + (size_t)(tn + rB) * K + csL * 8;
  }

#define STA(nb, mi, kb)                                                     \
  do {                                                                      \
    async_load16(gA[mi][0] + (kb), &sA[nb][mi][0] + tid * 8);               \
    async_load16(gA[mi][1] + (kb), &sA[nb][mi][0] + 4096 + tid * 8);        \
  } while (0)
#define STB(nb, ni, kb)                                                     \
  do {                                                                      \
    async_load16(gB[ni] + (kb), &sB[nb][ni][0] + tid * 8);                  \
  } while (0)
#define BARR()                                                              \
  do {                                                                      \
    asm volatile("" ::: "memory");                                          \
    __builtin_amdgcn_s_barrier();                                           \
    asm volatile("" ::: "memory");                                          \
  } while (0)
#define RDA(buf, mi)                                                        \
  do {                                                                      \
    const short* _p = &sA[buf][mi][0];                                      \
    _Pragma("unroll") for (int m = 0; m < 2; m++)                           \
        _Pragma("unroll") for (int ks = 0; ks < 2; ks++)                    \
            af[m][ks] = *(const bf16x8*)(_p + (wr * 32 + m * 16 + l15) * 64 \
                              + ((ks * 4 + quad) ^ (l15 & 7)) * 8);         \
  } while (0)
#define RDB(buf, ni)                                                        \
  do {                                                                      \
    const short* _p = &sB[buf][ni][0];                                      \
    _Pragma("unroll") for (int n = 0; n < 2; n++)                           \
        _Pragma("unroll") for (int ks = 0; ks < 2; ks++)                    \
            bfr[n][ks] = *(const bf16x8*)(_p + (wc * 32 + n * 16 + l15) * 64 \
                              + ((ks * 4 + quad) ^ (l15 & 7)) * 8);         \
  } while (0)
#define MM8(mi, ni)                                                         \
  do {                                                                      \
    __builtin_amdgcn_s_setprio(1);                                          \
    _Pragma("unroll") for (int m = 0; m < 2; m++)                           \
        _Pragma("unroll") for (int n = 0; n < 2; n++) {                     \
      acc[(mi)*2 + m][(ni)*2 + n] = __builtin_amdgcn_mfma_f32_16x16x32_bf16( \
          af[m][0], bfr[n][0], acc[(mi)*2 + m][(ni)*2 + n], 0, 0, 0);       \
      acc[(mi)*2 + m][(ni)*2 + n] = __builtin_amdgcn_mfma_f32_16x16x32_bf16( \
          af[m][1], bfr[n][1], acc[(mi)*2 + m][(ni)*2 + n], 0, 0, 0);       \
    }                                                                       \
    __builtin_amdgcn_s_setprio(0);                                          \
  } while (0)

  floatx4 acc[4][4];
#pragma unroll
  for (int i = 0; i < 4; i++)
#pragma unroll
    for (int j = 0; j < 4; j++) acc[i][j] = {0.f, 0.f, 0.f, 0.f};
  bf16x8 af[2][2], bfr[2][2];

  const int nk = K / BK;

  // prologue: tile 0, issue order matches steady-state ledger
  STB(0, 1, 0);
  STA(0, 0, 0);
  STB(0, 0, 0);
  STA(0, 1, 0);

  for (int t = 0; t < nk - 1; ++t) {
    const int buf = t & 1, nb = buf ^ 1;
    const int kb2 = (t + 1) * BK;
    // P0 (m0,n1): stage Bn1(t+1); need Am0(t),Bn1(t)
    STB(nb, 1, kb2);
    asm volatile("s_waitcnt vmcnt(4)" ::: "memory");
    BARR();
    RDA(buf, 0);
    RDB(buf, 1);
    MM8(0, 1);
    BARR();
    // P1 (m0,n0): stage Am0(t+1); need Bn0(t)  (af persists)
    STA(nb, 0, kb2);
    asm volatile("s_waitcnt vmcnt(5)" ::: "memory");
    BARR();
    RDB(buf, 0);
    MM8(0, 0);
    BARR();
    // P2 (m1,n0): stage Bn0(t+1); need Am1(t)  (bfr persists)
    STB(nb, 0, kb2);
    asm volatile("s_waitcnt vmcnt(4)" ::: "memory");
    BARR();
    RDA(buf, 1);
    MM8(1, 0);
    BARR();
    // P3 (m1,n1): stage Am1(t+1); all data already ensured
    STA(nb, 1, kb2);
    BARR();
    RDB(buf, 1);
    MM8(1, 1);
    BARR();
  }
  // peeled last tile (no staging; exact waits)
  {
    const int buf = (nk - 1) & 1;
    asm volatile("s_waitcnt vmcnt(3)" ::: "memory");
    BARR();
    RDA(buf, 0);
    RDB(buf, 1);
    MM8(0, 1);
    BARR();
    asm volatile("s_waitcnt vmcnt(2)" ::: "memory");
    BARR();
    RDB(buf, 0);
    MM8(0, 0);
    BARR();
    asm volatile("s_waitcnt vmcnt(0)" ::: "memory");
    BARR();
    RDA(buf, 1);
    MM8(1, 0);
    BARR();
    RDB(buf, 1);
    MM8(1, 1);
  }
#undef STA
#undef STB
#undef BARR
#undef RDA
#undef RDB
#undef MM8

#pragma unroll
  for (int mi = 0; mi < 2; mi++)
#pragma unroll
    for (int m = 0; m < 2; m++)
#pragma unroll
      for (int ni = 0; ni < 2; ni++)
#pragma unroll
        for (int n = 0; n < 2; n++)
#pragma unroll
          for (int r = 0; r < 4; r++) {
            const int row = tm + wr * 64 + mi * 32 + m * 16 + quad * 4 + r;
            const int col = tn + wc * 64 + ni * 32 + n * 16 + l15;
            storeC(C, (size_t)row * N + col, acc[mi * 2 + m][ni * 2 + n][r]);
          }
}

// Load one q row's two A-operand fragments with NeoX RoPE applied on the fly.
// Fragment elem j covers k-dim d = ks*32 + quad*8 + j; inputs at row[2i],row[2i+1],
// i = quad*8+j. HW transcendentals: v_sin/v_cos take REVOLUTIONS; reduce with
// fract first. freq8 pre-divided by 2pi. (Round 7: libm sincos here = +320 us.)
__device__ __forceinline__ void rope_frag(const bf16* __restrict__ row, int quad,
                                          float l_pos, const float* __restrict__ freq8,
                                          bf16x8* f0, bf16x8* f1) {
  const bf16x8 w0 = *(const bf16x8*)(const void*)(row + quad * 16);
  const bf16x8 w1 = *(const bf16x8*)(const void*)(row + quad * 16 + 8);
#pragma unroll
  for (int j = 0; j < 8; j++) {
    const short s1 = (j < 4) ? w0[2 * j] : w1[2 * (j - 4)];
    const short s2 = (j < 4) ? w0[2 * j + 1] : w1[2 * (j - 4) + 1];
    const float x1 = bf2f(s1), x2 = bf2f(s2);
    const float rev = l_pos * freq8[j];
    const float fr = rev - floorf(rev);
    const float c = __builtin_amdgcn_cosf(fr);
    const float s = __builtin_amdgcn_sinf(fr);
    (*f0)[j] = f2bf(x1 * c - x2 * s);
    (*f1)[j] = f2bf(x2 * c + x1 * s);
  }
}

// One block per (blk, h, b): 256x256 causal attention within the block.
// Roped K staged in LDS ONCE per block. kR stride 72 keeps 16B alignment and
// makes the 16-lane fragment read stride 36 dwords (2-way alias = free, m136).
// LDS: vT 32K + kR 36K + pS 8K = 76 KB -> 2 blocks/CU; grid 512 = 256 CU x 2
// exactly co-resident. (Round 9 bug: kw[4] loaded only half the 64-elem K row
// -> OOB reads of kw in the rope loop -> garbage upper-half K. Fixed: kw[8].)
__global__ __launch_bounds__(256) void attn_kernel(const bf16* __restrict__ qkv,
                                                   bf16* __restrict__ aout) {
  constexpr float SCALE = 0.125f;  // 64^-0.5
  constexpr float LOG2E = 1.4426950408889634f;
  constexpr float INV2PI = 0.15915494309189535f;
  __shared__ __align__(16) short vT[HD * BS];      // 32 KB: vT[d][key]
  __shared__ __align__(16) short kR[BS * KRP];     // 36 KB: roped K rows (padded)
  __shared__ __align__(16) short pS[4][16 * 64];   // 8 KB: per-wave P scratch (16 rows)
  const int blk = blockIdx.x, h = blockIdx.y, b = blockIdx.z;
  const int tid = threadIdx.x;
  const int wave = tid >> 6, lane = tid & 63;
  const int quad = lane >> 4, l15 = lane & 15;
  const size_t row0 = (size_t)(b * Ls + blk * BS);
  const bf16* qkvR = qkv + row0 * QKVROW;

  // inv_freq (revolutions) for this lane's q-fragment positions: i = quad*8+j
  float freq8[8];
#pragma unroll
  for (int j = 0; j < 8; j++)
    freq8[j] = exp2f(-13.287712379549449f * (float)(2 * (quad * 8 + j)) * (1.0f / 64.0f))
               * INV2PI;

  // stage V^T: thread tid handles key = tid (V is NOT roped)
  {
    const bf16* vrow = qkvR + (size_t)tid * QKVROW + 2 * Dm + h * HD;
#pragma unroll
    for (int i = 0; i < 8; i++) {
      bf16x8 vv = *(const bf16x8*)(vrow + i * 8);
#pragma unroll
      for (int e = 0; e < 8; e++) vT[(i * 8 + e) * BS + tid] = vv[e];
    }
  }

  // stage roped K: thread tid ropes the FULL 64-elem key-row tid (once/block)
  {
    const bf16* krow = qkvR + (size_t)tid * QKVROW + Dm + h * HD;
    bf16x8 kw[8];
#pragma unroll
    for (int t = 0; t < 8; t++) kw[t] = *(const bf16x8*)(krow + t * 8);
    const float pos = (float)(blk * BS + tid);
    short tmp[64];
#pragma unroll
    for (int i = 0; i < 32; i++) {
      const float x1 = bf2f(kw[(2 * i) >> 3][(2 * i) & 7]);
      const float x2 = bf2f(kw[(2 * i + 1) >> 3][(2 * i + 1) & 7]);
      const float fq = exp2f(-13.287712379549449f * (float)(2 * i) * (1.0f / 64.0f)) * INV2PI;
      const float rev = pos * fq;
      const float fr = rev - floorf(rev);
      const float c = __builtin_amdgcn_cosf(fr);
      const float s = __builtin_amdgcn_sinf(fr);
      tmp[i]      = f2bf(x1 * c - x2 * s);
      tmp[i + 32] = f2bf(x2 * c + x1 * s);
    }
#pragma unroll
    for (int t = 0; t < 8; t++)
      *(bf16x8*)(kR + tid * KRP + t * 8) = *(const bf16x8*)(tmp + t * 8);
  }
  __syncthreads();  // vT + kR ready; no block barrier past this point

  short* myP = &pS[wave][0];

  for (int sp = 0; sp < 2; sp++) {
    const int s = sp ? (7 - wave) : wave;  // strip index 0..7
    const int qrow0 = s * 32;
    const int kcmax = s >> 1;

    // roped q fragments for this strip: A-layout m=lane&15, k=quad*8+j
    bf16x8 qf[2][2];
#pragma unroll
    for (int mt = 0; mt < 2; mt++) {
      const int qr = qrow0 + mt * 16 + l15;
      rope_frag(qkvR + (size_t)qr * QKVROW + h * HD, quad,
                (float)(blk * BS + qr), freq8, &qf[mt][0], &qf[mt][1]);
    }

    float m_i[2][4], l_i[2][4];
    floatx4 o[2][4];
#pragma unroll
    for (int mt = 0; mt < 2; mt++)
#pragma unroll
      for (int r = 0; r < 4; r++) { m_i[mt][r] = -1e30f; l_i[mt][r] = 0.f; }
#pragma unroll
    for (int mt = 0; mt < 2; mt++)
#pragma unroll
      for (int nt = 0; nt < 4; nt++) o[mt][nt] = {0.f, 0.f, 0.f, 0.f};

    for (int kc = 0; kc <= kcmax; kc++) {
      floatx4 sc[2][4];
#pragma unroll
      for (int mt = 0; mt < 2; mt++)
#pragma unroll
        for (int nt = 0; nt < 4; nt++) sc[mt][nt] = {0.f, 0.f, 0.f, 0.f};

      // roped k fragments from LDS: B-row = kc*64+nt*16+l15, elem ks*32+quad*8+j
      bf16x8 kf[4][2];
#pragma unroll
      for (int nt = 0; nt < 4; nt++) {
        const short* kr = kR + (kc * 64 + nt * 16 + l15) * KRP;
        kf[nt][0] = *(const bf16x8*)(kr + quad * 8);
        kf[nt][1] = *(const bf16x8*)(kr + 32 + quad * 8);
      }

#pragma unroll
      for (int mt = 0; mt < 2; mt++)
#pragma unroll
        for (int nt = 0; nt < 4; nt++) {
          sc[mt][nt] = __builtin_amdgcn_mfma_f32_16x16x32_bf16(qf[mt][0], kf[nt][0], sc[mt][nt], 0, 0, 0);
          sc[mt][nt] = __builtin_amdgcn_mfma_f32_16x16x32_bf16(qf[mt][1], kf[nt][1], sc[mt][nt], 0, 0, 0);
        }

      const bool diag = (kc == kcmax);
#pragma unroll
      for (int mt = 0; mt < 2; mt++)
#pragma unroll
        for (int r = 0; r < 4; r++) {
          const int rowg = qrow0 + mt * 16 + quad * 4 + r;
          float cmax = -1e30f;
#pragma unroll
          for (int nt = 0; nt < 4; nt++) {
            float sv = sc[mt][nt][r] * SCALE;
            if (diag && (kc * 64 + nt * 16 + l15 > rowg)) sv = -1e30f;
            sc[mt][nt][r] = sv;
            cmax = fmaxf(cmax, sv);
          }
#pragma unroll
          for (int off = 1; off < 16; off <<= 1)
            cmax = fmaxf(cmax, __shfl_xor(cmax, off, 64));  // 16 lanes share a row
          const float mold = m_i[mt][r];
          const float mnew = fmaxf(mold, cmax);
          const float alpha = exp2f((mold - mnew) * LOG2E);
          float rsum = 0.f;
#pragma unroll
          for (int nt = 0; nt < 4; nt++) {
            const float p = exp2f((sc[mt][nt][r] - mnew) * LOG2E);
            sc[mt][nt][r] = p;
            rsum += p;
          }
#pragma unroll
          for (int off = 1; off < 16; off <<= 1)
            rsum += __shfl_xor(rsum, off, 64);
          l_i[mt][r] = l_i[mt][r] * alpha + rsum;
          m_i[mt][r] = mnew;
#pragma unroll
          for (int nt = 0; nt < 4; nt++) o[mt][nt][r] *= alpha;
        }

      // V fragments for this key-chunk
      bf16x8 vf0[4], vf1[4];
#pragma unroll
      for (int nt = 0; nt < 4; nt++) {
        vf0[nt] = *(const bf16x8*)(vT + (nt * 16 + l15) * BS + kc * 64 + quad * 8);
        vf1[nt] = *(const bf16x8*)(vT + (nt * 16 + l15) * BS + kc * 64 + 32 + quad * 8);
      }

      // P: C-layout -> LDS -> A-layout, one 16-row mt-half at a time
      // (wave-private buffer; per-wave DS ops are in-order)
#pragma unroll
      for (int mt = 0; mt < 2; mt++) {
#pragma unroll
        for (int nt = 0; nt < 4; nt++)
#pragma unroll
          for (int r = 0; r < 4; r++)
            myP[(quad * 4 + r) * 64 + nt * 16 + l15] = f2bf(sc[mt][nt][r]);
        __asm__ __volatile__("s_waitcnt lgkmcnt(0)" ::: "memory");
        const bf16x8 pf0 = *(const bf16x8*)(myP + l15 * 64 + quad * 8);
        const bf16x8 pf1 = *(const bf16x8*)(myP + l15 * 64 + 32 + quad * 8);
#pragma unroll
        for (int nt = 0; nt < 4; nt++) {
          o[mt][nt] = __builtin_amdgcn_mfma_f32_16x16x32_bf16(pf0, vf0[nt], o[mt][nt], 0, 0, 0);
          o[mt][nt] = __builtin_amdgcn_mfma_f32_16x16x32_bf16(pf1, vf1[nt], o[mt][nt], 0, 0, 0);
        }
        __asm__ __volatile__("s_waitcnt lgkmcnt(0)" ::: "memory");  // reads done before overwrite
      }
    }

    // normalize and store strip (B,L,H,HD) -> row-major (B*L, 1024)
#pragma unroll
    for (int mt = 0; mt < 2; mt++)
#pragma unroll
      for (int r = 0; r < 4; r++) {
        const float inv = 1.0f / l_i[mt][r];
#pragma unroll
        for (int nt = 0; nt < 4; nt++) {
          const size_t m = row0 + qrow0 + mt * 16 + quad * 4 + r;
          aout[m * Dm + h * HD + nt * 16 + l15] = __float2bfloat16(o[mt][nt][r] * inv);
        }
      }
  }
}

extern "C" void kernel_launch(void* const* d_in, const int* in_sizes, int n_in,
                              void* d_out, int out_size, void* d_ws, size_t ws_size,
                              hipStream_t stream) {
  const float* x    = (const float*)d_in[0];   // (2,4096,1024) fp32
  const float* Wqkv = (const float*)d_in[1];   // (3072,1024) fp32
  const float* Wout = (const float*)d_in[2];   // (1024,1024) fp32
  float* out = (float*)d_out;                  // (2,4096,1024) fp32

  bf16* xb    = (bf16*)d_ws;        // 16.8 MB; dead after QKV GEMM -> reused as attnb
  bf16* qkv   = xb + NX;            // 50.3 MB
  bf16* Wqkvb = qkv + NQ;           // 6.3 MB
  bf16* Woutb = Wqkvb + NW1;        // 2.1 MB
  bf16* attnb = xb;                 // alias (xb dead by then)

  cvt3_kernel<<<(NX + NW1 + NW2) / 2048, 256, 0, stream>>>(x, Wqkv, Wout, xb, Wqkvb, Woutb);

  // grids: QKV 24x32 = 768 blocks = 3 exact CU-rounds; Wout 8x32 = 256 = 1 round
  gemm_8p<bf16>
      <<<dim3(3072 / 128, 8192 / 256), 512, 0, stream>>>(xb, Wqkvb, qkv, 8192, 3072, 1024);
  attn_kernel<<<dim3(Ls / BS, Hn, Bb), 256, 0, stream>>>(qkv, attnb);
  gemm_8p<float>
      <<<dim3(1024 / 128, 8192 / 256), 512, 0, stream>>>(attnb, Woutb, out, 8192, 1024, 1024);
}

// Round 3
// 214.232 us; speedup vs baseline: 1.1666x; 1.1666x over previous
//
#include <hip/hip_runtime.h>
#include <hip/hip_bf16.h>
#include <cstdint>
#include <cstddef>

typedef __hip_bfloat16 bf16;
typedef __attribute__((ext_vector_type(8))) short bf16x8;
typedef __attribute__((ext_vector_type(4))) float floatx4;

static constexpr int Bb = 2;
static constexpr int Ls = 4096;
static constexpr int Dm = 1024;
static constexpr int Hn = 16;
static constexpr int HD = 64;
static constexpr int BS = 256;
static constexpr int QKVROW = 3 * Dm;  // 3072
static constexpr int KRP = 72;         // padded roped-K row stride (16B-aligned, breaks bank stride)

static constexpr size_t NX  = (size_t)8192 * 1024;
static constexpr size_t NQ  = (size_t)8192 * 3072;
static constexpr size_t NW1 = (size_t)3072 * 1024;
static constexpr size_t NW2 = (size_t)1024 * 1024;

__device__ __forceinline__ void async_load16(const void* g, void* l) {
  __builtin_amdgcn_global_load_lds(
      (__attribute__((address_space(1))) void*)(void*)(g),
      (__attribute__((address_space(3))) void*)(l), 16, 0, 0);
}

__device__ __forceinline__ short f2bf(float f) {
  union { __hip_bfloat16 b; short s; } u;
  u.b = __float2bfloat16(f);
  return u.s;
}

__device__ __forceinline__ float bf2f(short s) {
  union { unsigned u; float f; } v;
  v.u = ((unsigned)(unsigned short)s) << 16;
  return v.f;
}

__device__ __forceinline__ bf16x8 load8(const float* p) {
  const float4 f0 = *(const float4*)(const void*)p;
  const float4 f1 = *(const float4*)(const void*)(p + 4);
  bf16x8 r;
  r[0] = f2bf(f0.x); r[1] = f2bf(f0.y); r[2] = f2bf(f0.z); r[3] = f2bf(f0.w);
  r[4] = f2bf(f1.x); r[5] = f2bf(f1.y); r[6] = f2bf(f1.z); r[7] = f2bf(f1.w);
  return r;
}

__device__ __forceinline__ void storeC(bf16* C, size_t idx, float v) {
  C[idx] = __float2bfloat16(v);
}
__device__ __forceinline__ void storeC(float* C, size_t idx, float v) {
  C[idx] = v;
}

// Merged fp32->bf16 convert for x, Wqkv, Wout (regions 2048-aligned; block-uniform branch).
__global__ void cvt3_kernel(const float* __restrict__ x, const float* __restrict__ w1,
                            const float* __restrict__ w2, bf16* __restrict__ xb,
                            bf16* __restrict__ w1b, bf16* __restrict__ w2b) {
  const size_t i = ((size_t)blockIdx.x * 256 + threadIdx.x) * 8;
  if (i < NX) {
    *(bf16x8*)(void*)((short*)(void*)xb + i) = load8(x + i);
  } else if (i < NX + NW1) {
    const size_t k = i - NX;
    *(bf16x8*)(void*)((short*)(void*)w1b + k) = load8(w1 + k);
  } else {
    const size_t k = i - NX - NW1;
    *(bf16x8*)(void*)((short*)(void*)w2b + k) = load8(w2 + k);
  }
}

// ---------------------------------------------------------------------------
// 256x128 bf16 GEMM, m201-faithful phase schedule. C[m,n]=sum_k A[m,k]*B[n,k].
// M%256==0, N%128==0, K%64==0, K/64>=3.
//
// Round-2 post-mortem: my phases put ds_read AFTER the barrier, serially
// exposing LDS latency before each MFMA cluster (86.7us, MfmaUtil 22%). The
// m201 template's order is {ds_read -> stage -> [vmcnt] -> barrier ->
// lgkmcnt(0) -> MFMA -> barrier}: reads issue BEFORE the rendezvous so their
// latency hides under barrier skew + sibling-wave MFMA. This version restores
// that order exactly.
//
// Geometry: 8 waves 4Mx2N, per-wave 64x64, BK=64 -> 32 MFMA/K-tile/wave in
// 2 phases of 16 (m-half split; bfr[4][2] read once in P1, reused in P2).
// LDS: triple buffer (96K A + 48K B = 144 KB, 1 block/CU), stage tile t+2
// during tile t (prefetch distance 4 phases), 3 loads/thread/half.
// vmcnt ledger (T4): single vmcnt(6) in P2 -> newest 6 = H1(t+2)+H2(t+2),
// forces tile t+1 complete before its P1 reads (2 barriers later). Peeled
// tail drains once. WAR: buffer staged at t+2 last read at t-1 (>=4 barriers).
// T2 swizzle: phys slot = logical slot ^ (row&7) on the GLOBAL source at
// stage and on the ds_read address (same involution) -> conflict-free.
// T5 setprio around each MFMA cluster.
// ---------------------------------------------------------------------------
template <typename TC>
__global__ __launch_bounds__(512, 2) void gemm_8p(
    const bf16* __restrict__ A, const bf16* __restrict__ Bm, TC* __restrict__ C,
    int M, int N, int K) {
  constexpr int BK = 64;
  __shared__ __align__(16) short sA[3][256 * 64];  // 96 KB
  __shared__ __align__(16) short sB[3][128 * 64];  // 48 KB
  const int tid = threadIdx.x;
  const int wave = tid >> 6, lane = tid & 63;
  const int quad = lane >> 4, l15 = lane & 15;
  const int wr = wave >> 1, wc = wave & 1;
  const int tm = blockIdx.y * 256, tn = blockIdx.x * 128;

  // staging geometry: thread -> LDS row iLo(+64j), phys 16B slot csP; global
  // source pre-swizzled so phys slot csP holds logical slot csP^(row&7).
  const int iLo = tid >> 3;            // 0..63
  const int csP = tid & 7;
  const int csL = csP ^ (iLo & 7);
  const bf16* gA[4];
  const bf16* gB[2];
#pragma unroll
  for (int j = 0; j < 4; j++) gA[j] = A + (size_t)(tm + iLo + 64 * j) * K + csL * 8;
#pragma unroll
  for (int j = 0; j < 2; j++) gB[j] = Bm + (size_t)(tn + iLo + 64 * j) * K + csL * 8;

  short* aC  = &sA[0][0];
  short* aN1 = &sA[1][0];
  short* aN2 = &sA[2][0];
  short* bC  = &sB[0][0];
  short* bN1 = &sB[1][0];
  short* bN2 = &sB[2][0];

#define STH1(aD, bD, kb)                                   \
  do {                                                     \
    async_load16(gA[0] + (kb), (aD) + tid * 8);            \
    async_load16(gA[1] + (kb), (aD) + 4096 + tid * 8);     \
    async_load16(gB[0] + (kb), (bD) + tid * 8);            \
  } while (0)
#define STH2(aD, bD, kb)                                   \
  do {                                                     \
    async_load16(gA[2] + (kb), (aD) + 8192 + tid * 8);     \
    async_load16(gA[3] + (kb), (aD) + 12288 + tid * 8);    \
    async_load16(gB[1] + (kb), (bD) + 4096 + tid * 8);     \
  } while (0)
#define BARR()                                             \
  do {                                                     \
    asm volatile("" ::: "memory");                         \
    __builtin_amdgcn_s_barrier();                          \
    asm volatile("" ::: "memory");                         \
  } while (0)
#define LGKM0() asm volatile("s_waitcnt lgkmcnt(0)" ::: "memory")
#define RDB4(bP)                                                               \
  do {                                                                         \
    _Pragma("unroll") for (int n = 0; n < 4; n++)                              \
        _Pragma("unroll") for (int ks = 0; ks < 2; ks++)                       \
            bfr[n][ks] = *(const bf16x8*)((bP) + (wc * 64 + n * 16 + l15) * 64 \
                              + ((ks * 4 + quad) ^ (l15 & 7)) * 8);            \
  } while (0)
#define RDA2(aP, mh)                                                           \
  do {                                                                         \
    _Pragma("unroll") for (int mm = 0; mm < 2; mm++)                           \
        _Pragma("unroll") for (int ks = 0; ks < 2; ks++)                       \
            af[mm][ks] = *(const bf16x8*)(                                     \
                (aP) + (wr * 64 + ((mh)*2 + mm) * 16 + l15) * 64               \
                + ((ks * 4 + quad) ^ (l15 & 7)) * 8);                          \
  } while (0)
#define MM16(mh)                                                               \
  do {                                                                         \
    __builtin_amdgcn_s_setprio(1);                                             \
    _Pragma("unroll") for (int mm = 0; mm < 2; mm++)                           \
        _Pragma("unroll") for (int n = 0; n < 4; n++) {                        \
      acc[(mh)*2 + mm][n] = __builtin_amdgcn_mfma_f32_16x16x32_bf16(           \
          af[mm][0], bfr[n][0], acc[(mh)*2 + mm][n], 0, 0, 0);                 \
      acc[(mh)*2 + mm][n] = __builtin_amdgcn_mfma_f32_16x16x32_bf16(           \
          af[mm][1], bfr[n][1], acc[(mh)*2 + mm][n], 0, 0, 0);                 \
    }                                                                          \
    __builtin_amdgcn_s_setprio(0);                                             \
  } while (0)

  floatx4 acc[4][4];
#pragma unroll
  for (int i = 0; i < 4; i++)
#pragma unroll
    for (int j = 0; j < 4; j++) acc[i][j] = {0.f, 0.f, 0.f, 0.f};
  bf16x8 af[2][2], bfr[4][2];

  const int nk = K / BK;

  // prologue: tiles 0,1 staged; vmcnt(6) -> tile 0 complete (newest 6 = tile 1)
  STH1(aC, bC, 0);
  STH2(aC, bC, 0);
  STH1(aN1, bN1, BK);
  STH2(aN1, bN1, BK);
  asm volatile("s_waitcnt vmcnt(6)" ::: "memory");
  BARR();

  for (int t = 0; t < nk - 2; ++t) {
    const int kb2 = (t + 2) * BK;
    // P1: reads (12) -> stage H1(t+2) -> barrier -> MFMA m-lo
    RDB4(bC);
    RDA2(aC, 0);
    STH1(aN2, bN2, kb2);
    BARR();
    LGKM0();
    MM16(0);
    BARR();
    // P2: reads (4) -> stage H2(t+2) -> vmcnt(6) [tile t+1 resident] -> MFMA m-hi
    RDA2(aC, 1);
    STH2(aN2, bN2, kb2);
    asm volatile("s_waitcnt vmcnt(6)" ::: "memory");
    BARR();
    LGKM0();
    MM16(1);
    BARR();
    // rotate ring
    short* ta = aC; aC = aN1; aN1 = aN2; aN2 = ta;
    short* tb = bC; bC = bN1; bN1 = bN2; bN2 = tb;
  }
  // t = nk-2 (resident; tile nk-1's 6 loads outstanding)
  RDB4(bC);
  RDA2(aC, 0);
  BARR();
  LGKM0();
  MM16(0);
  BARR();
  RDA2(aC, 1);
  asm volatile("s_waitcnt vmcnt(0)" ::: "memory");
  BARR();
  LGKM0();
  MM16(1);
  BARR();
  {
    short* ta = aC; aC = aN1; aN1 = aN2; aN2 = ta;
    short* tb = bC; bC = bN1; bN1 = bN2; bN2 = tb;
  }
  // t = nk-1 (all resident, no staging)
  RDB4(bC);
  RDA2(aC, 0);
  LGKM0();
  MM16(0);
  RDA2(aC, 1);
  LGKM0();
  MM16(1);
#undef STH1
#undef STH2
#undef BARR
#undef LGKM0
#undef RDB4
#undef RDA2
#undef MM16

#pragma unroll
  for (int m = 0; m < 4; m++)
#pragma unroll
    for (int n = 0; n < 4; n++)
#pragma unroll
      for (int r = 0; r < 4; r++) {
        const int row = tm + wr * 64 + m * 16 + quad * 4 + r;  // C/D: row=quad*4+r
        const int col = tn + wc * 64 + n * 16 + l15;           //      col=lane&15
        storeC(C, (size_t)row * N + col, acc[m][n][r]);
      }
}

// Load one q row's two A-operand fragments with NeoX RoPE applied on the fly.
// Fragment elem j covers k-dim d = ks*32 + quad*8 + j; inputs at row[2i],row[2i+1],
// i = quad*8+j. HW transcendentals: v_sin/v_cos take REVOLUTIONS; reduce with
// fract first. freq8 pre-divided by 2pi. (Round 7: libm sincos here = +320 us.)
__device__ __forceinline__ void rope_frag(const bf16* __restrict__ row, int quad,
                                          float l_pos, const float* __restrict__ freq8,
                                          bf16x8* f0, bf16x8* f1) {
  const bf16x8 w0 = *(const bf16x8*)(const void*)(row + quad * 16);
  const bf16x8 w1 = *(const bf16x8*)(const void*)(row + quad * 16 + 8);
#pragma unroll
  for (int j = 0; j < 8; j++) {
    const short s1 = (j < 4) ? w0[2 * j] : w1[2 * (j - 4)];
    const short s2 = (j < 4) ? w0[2 * j + 1] : w1[2 * (j - 4) + 1];
    const float x1 = bf2f(s1), x2 = bf2f(s2);
    const float rev = l_pos * freq8[j];
    const float fr = rev - floorf(rev);
    const float c = __builtin_amdgcn_cosf(fr);
    const float s = __builtin_amdgcn_sinf(fr);
    (*f0)[j] = f2bf(x1 * c - x2 * s);
    (*f1)[j] = f2bf(x2 * c + x1 * s);
  }
}

// One block per (blk, h, b): 256x256 causal attention within the block.
// Roped K staged in LDS ONCE per block. kR stride 72 keeps 16B alignment and
// makes the 16-lane fragment read stride 36 dwords (2-way alias = free, m136).
// LDS: vT 32K + kR 36K + pS 8K = 76 KB -> 2 blocks/CU; grid 512 = 256 CU x 2
// exactly co-resident. (Round 9 bug: kw[4] loaded only half the 64-elem K row
// -> OOB reads of kw in the rope loop -> garbage upper-half K. Fixed: kw[8].)
__global__ __launch_bounds__(256) void attn_kernel(const bf16* __restrict__ qkv,
                                                   bf16* __restrict__ aout) {
  constexpr float SCALE = 0.125f;  // 64^-0.5
  constexpr float LOG2E = 1.4426950408889634f;
  constexpr float INV2PI = 0.15915494309189535f;
  __shared__ __align__(16) short vT[HD * BS];      // 32 KB: vT[d][key]
  __shared__ __align__(16) short kR[BS * KRP];     // 36 KB: roped K rows (padded)
  __shared__ __align__(16) short pS[4][16 * 64];   // 8 KB: per-wave P scratch (16 rows)
  const int blk = blockIdx.x, h = blockIdx.y, b = blockIdx.z;
  const int tid = threadIdx.x;
  const int wave = tid >> 6, lane = tid & 63;
  const int quad = lane >> 4, l15 = lane & 15;
  const size_t row0 = (size_t)(b * Ls + blk * BS);
  const bf16* qkvR = qkv + row0 * QKVROW;

  // inv_freq (revolutions) for this lane's q-fragment positions: i = quad*8+j
  float freq8[8];
#pragma unroll
  for (int j = 0; j < 8; j++)
    freq8[j] = exp2f(-13.287712379549449f * (float)(2 * (quad * 8 + j)) * (1.0f / 64.0f))
               * INV2PI;

  // stage V^T: thread tid handles key = tid (V is NOT roped)
  {
    const bf16* vrow = qkvR + (size_t)tid * QKVROW + 2 * Dm + h * HD;
#pragma unroll
    for (int i = 0; i < 8; i++) {
      bf16x8 vv = *(const bf16x8*)(vrow + i * 8);
#pragma unroll
      for (int e = 0; e < 8; e++) vT[(i * 8 + e) * BS + tid] = vv[e];
    }
  }

  // stage roped K: thread tid ropes the FULL 64-elem key-row tid (once/block)
  {
    const bf16* krow = qkvR + (size_t)tid * QKVROW + Dm + h * HD;
    bf16x8 kw[8];
#pragma unroll
    for (int t = 0; t < 8; t++) kw[t] = *(const bf16x8*)(krow + t * 8);
    const float pos = (float)(blk * BS + tid);
    short tmp[64];
#pragma unroll
    for (int i = 0; i < 32; i++) {
      const float x1 = bf2f(kw[(2 * i) >> 3][(2 * i) & 7]);
      const float x2 = bf2f(kw[(2 * i + 1) >> 3][(2 * i + 1) & 7]);
      const float fq = exp2f(-13.287712379549449f * (float)(2 * i) * (1.0f / 64.0f)) * INV2PI;
      const float rev = pos * fq;
      const float fr = rev - floorf(rev);
      const float c = __builtin_amdgcn_cosf(fr);
      const float s = __builtin_amdgcn_sinf(fr);
      tmp[i]      = f2bf(x1 * c - x2 * s);
      tmp[i + 32] = f2bf(x2 * c + x1 * s);
    }
#pragma unroll
    for (int t = 0; t < 8; t++)
      *(bf16x8*)(kR + tid * KRP + t * 8) = *(const bf16x8*)(tmp + t * 8);
  }
  __syncthreads();  // vT + kR ready; no block barrier past this point

  short* myP = &pS[wave][0];

  for (int sp = 0; sp < 2; sp++) {
    const int s = sp ? (7 - wave) : wave;  // strip index 0..7
    const int qrow0 = s * 32;
    const int kcmax = s >> 1;

    // roped q fragments for this strip: A-layout m=lane&15, k=quad*8+j
    bf16x8 qf[2][2];
#pragma unroll
    for (int mt = 0; mt < 2; mt++) {
      const int qr = qrow0 + mt * 16 + l15;
      rope_frag(qkvR + (size_t)qr * QKVROW + h * HD, quad,
                (float)(blk * BS + qr), freq8, &qf[mt][0], &qf[mt][1]);
    }

    float m_i[2][4], l_i[2][4];
    floatx4 o[2][4];
#pragma unroll
    for (int mt = 0; mt < 2; mt++)
#pragma unroll
      for (int r = 0; r < 4; r++) { m_i[mt][r] = -1e30f; l_i[mt][r] = 0.f; }
#pragma unroll
    for (int mt = 0; mt < 2; mt++)
#pragma unroll
      for (int nt = 0; nt < 4; nt++) o[mt][nt] = {0.f, 0.f, 0.f, 0.f};

    for (int kc = 0; kc <= kcmax; kc++) {
      floatx4 sc[2][4];
#pragma unroll
      for (int mt = 0; mt < 2; mt++)
#pragma unroll
        for (int nt = 0; nt < 4; nt++) sc[mt][nt] = {0.f, 0.f, 0.f, 0.f};

      // roped k fragments from LDS: B-row = kc*64+nt*16+l15, elem ks*32+quad*8+j
      bf16x8 kf[4][2];
#pragma unroll
      for (int nt = 0; nt < 4; nt++) {
        const short* kr = kR + (kc * 64 + nt * 16 + l15) * KRP;
        kf[nt][0] = *(const bf16x8*)(kr + quad * 8);
        kf[nt][1] = *(const bf16x8*)(kr + 32 + quad * 8);
      }

#pragma unroll
      for (int mt = 0; mt < 2; mt++)
#pragma unroll
        for (int nt = 0; nt < 4; nt++) {
          sc[mt][nt] = __builtin_amdgcn_mfma_f32_16x16x32_bf16(qf[mt][0], kf[nt][0], sc[mt][nt], 0, 0, 0);
          sc[mt][nt] = __builtin_amdgcn_mfma_f32_16x16x32_bf16(qf[mt][1], kf[nt][1], sc[mt][nt], 0, 0, 0);
        }

      const bool diag = (kc == kcmax);
#pragma unroll
      for (int mt = 0; mt < 2; mt++)
#pragma unroll
        for (int r = 0; r < 4; r++) {
          const int rowg = qrow0 + mt * 16 + quad * 4 + r;
          float cmax = -1e30f;
#pragma unroll
          for (int nt = 0; nt < 4; nt++) {
            float sv = sc[mt][nt][r] * SCALE;
            if (diag && (kc * 64 + nt * 16 + l15 > rowg)) sv = -1e30f;
            sc[mt][nt][r] = sv;
            cmax = fmaxf(cmax, sv);
          }
#pragma unroll
          for (int off = 1; off < 16; off <<= 1)
            cmax = fmaxf(cmax, __shfl_xor(cmax, off, 64));  // 16 lanes share a row
          const float mold = m_i[mt][r];
          const float mnew = fmaxf(mold, cmax);
          const float alpha = exp2f((mold - mnew) * LOG2E);
          float rsum = 0.f;
#pragma unroll
          for (int nt = 0; nt < 4; nt++) {
            const float p = exp2f((sc[mt][nt][r] - mnew) * LOG2E);
            sc[mt][nt][r] = p;
            rsum += p;
          }
#pragma unroll
          for (int off = 1; off < 16; off <<= 1)
            rsum += __shfl_xor(rsum, off, 64);
          l_i[mt][r] = l_i[mt][r] * alpha + rsum;
          m_i[mt][r] = mnew;
#pragma unroll
          for (int nt = 0; nt < 4; nt++) o[mt][nt][r] *= alpha;
        }

      // V fragments for this key-chunk
      bf16x8 vf0[4], vf1[4];
#pragma unroll
      for (int nt = 0; nt < 4; nt++) {
        vf0[nt] = *(const bf16x8*)(vT + (nt * 16 + l15) * BS + kc * 64 + quad * 8);
        vf1[nt] = *(const bf16x8*)(vT + (nt * 16 + l15) * BS + kc * 64 + 32 + quad * 8);
      }

      // P: C-layout -> LDS -> A-layout, one 16-row mt-half at a time
      // (wave-private buffer; per-wave DS ops are in-order)
#pragma unroll
      for (int mt = 0; mt < 2; mt++) {
#pragma unroll
        for (int nt = 0; nt < 4; nt++)
#pragma unroll
          for (int r = 0; r < 4; r++)
            myP[(quad * 4 + r) * 64 + nt * 16 + l15] = f2bf(sc[mt][nt][r]);
        __asm__ __volatile__("s_waitcnt lgkmcnt(0)" ::: "memory");
        const bf16x8 pf0 = *(const bf16x8*)(myP + l15 * 64 + quad * 8);
        const bf16x8 pf1 = *(const bf16x8*)(myP + l15 * 64 + 32 + quad * 8);
#pragma unroll
        for (int nt = 0; nt < 4; nt++) {
          o[mt][nt] = __builtin_amdgcn_mfma_f32_16x16x32_bf16(pf0, vf0[nt], o[mt][nt], 0, 0, 0);
          o[mt][nt] = __builtin_amdgcn_mfma_f32_16x16x32_bf16(pf1, vf1[nt], o[mt][nt], 0, 0, 0);
        }
        __asm__ __volatile__("s_waitcnt lgkmcnt(0)" ::: "memory");  // reads done before overwrite
      }
    }

    // normalize and store strip (B,L,H,HD) -> row-major (B*L, 1024)
#pragma unroll
    for (int mt = 0; mt < 2; mt++)
#pragma unroll
      for (int r = 0; r < 4; r++) {
        const float inv = 1.0f / l_i[mt][r];
#pragma unroll
        for (int nt = 0; nt < 4; nt++) {
          const size_t m = row0 + qrow0 + mt * 16 + quad * 4 + r;
          aout[m * Dm + h * HD + nt * 16 + l15] = __float2bfloat16(o[mt][nt][r] * inv);
        }
      }
  }
}

extern "C" void kernel_launch(void* const* d_in, const int* in_sizes, int n_in,
                              void* d_out, int out_size, void* d_ws, size_t ws_size,
                              hipStream_t stream) {
  const float* x    = (const float*)d_in[0];   // (2,4096,1024) fp32
  const float* Wqkv = (const float*)d_in[1];   // (3072,1024) fp32
  const float* Wout = (const float*)d_in[2];   // (1024,1024) fp32
  float* out = (float*)d_out;                  // (2,4096,1024) fp32

  bf16* xb    = (bf16*)d_ws;        // 16.8 MB; dead after QKV GEMM -> reused as attnb
  bf16* qkv   = xb + NX;            // 50.3 MB
  bf16* Wqkvb = qkv + NQ;           // 6.3 MB
  bf16* Woutb = Wqkvb + NW1;        // 2.1 MB
  bf16* attnb = xb;                 // alias (xb dead by then)

  cvt3_kernel<<<(NX + NW1 + NW2) / 2048, 256, 0, stream>>>(x, Wqkv, Wout, xb, Wqkvb, Woutb);

  // grids: QKV 24x32 = 768 blocks = 3 exact CU-rounds; Wout 8x32 = 256 = 1 round
  gemm_8p<bf16>
      <<<dim3(3072 / 128, 8192 / 256), 512, 0, stream>>>(xb, Wqkvb, qkv, 8192, 3072, 1024);
  attn_kernel<<<dim3(Ls / BS, Hn, Bb), 256, 0, stream>>>(qkv, attnb);
  gemm_8p<float>
      <<<dim3(1024 / 128, 8192 / 256), 512, 0, stream>>>(attnb, Woutb, out, 8192, 1024, 1024);
}